// Round 10
// baseline (172.643 us; speedup 1.0000x reference)
//
#include <hip/hip_runtime.h>
#include <hip/hip_bf16.h>
#include <math.h>

namespace {
constexpr int kB  = 64;
constexpr int kNi = 2048;
constexpr int kNo = 32;
constexpr int kDo = 16;
constexpr int kSeg   = kNo * kDo;      // 512 od
constexpr int kSlabs = 256;            // n-slabs
constexpr int kNPer  = kNi / kSlabs;   // 8 n per slab
}

typedef __attribute__((ext_vector_type(4)))  short s4;    // 4 bf16 (2 VGPR)
typedef __attribute__((ext_vector_type(16))) float f16v;  // MFMA C/D

__device__ __forceinline__ f16v mfma_32x32x8_bf16(s4 a, s4 b, f16v c) {
#if __has_builtin(__builtin_amdgcn_mfma_f32_32x32x8bf16_1k)
    return __builtin_amdgcn_mfma_f32_32x32x8bf16_1k(a, b, c, 0, 0, 0);
#else
    asm("v_mfma_f32_32x32x8_bf16 %0, %1, %2, %0" : "+v"(c) : "v"(a), "v"(b));
    return c;
#endif
}

__device__ __forceinline__ unsigned pack_bf16(float lo, float hi) {
    union { __hip_bfloat162 h; unsigned u; } v;
    v.h = __float22bfloat162_rn(make_float2(lo, hi));
    return v.u;
}

union A2 { int2 i; s4 s; };

// ---------------------------------------------------------------------------
// Prep: pack W and x into 32x32x8 MFMA fragment order, bf16.
// wPack2: a wave's TWO m-tile frags contiguous ->
//   int4 index ((n*8 + w)*64 + l): slots {0,1} = mt=2w, {2,3} = mt=2w+1,
//   frag value = W[n][mt*32+(l&31)][4*(l>>5)+j].
// xPack: int2 index ((n*2+nt)*64 + l) = x[nt*32+(l&31)][n][4*(l>>5)+j].
// ---------------------------------------------------------------------------
__global__ __launch_bounds__(256, 4)
void caps_prep(const float* __restrict__ xg, const float* __restrict__ Wg,
               unsigned* __restrict__ wPack2, unsigned* __restrict__ xPack)
{
    const int t = blockIdx.x * 256 + threadIdx.x;
    const int nW = kNi * 16 * 64;                  // 2,097,152 frag-lanes
    if (t < nW) {
        const int n = t >> 10, rem = t & 1023, mt = rem >> 6, l = rem & 63;
        const float4 w = *reinterpret_cast<const float4*>(
            Wg + ((size_t)n * kSeg + mt * 32 + (l & 31)) * 8 + 4 * (l >> 5));
        const size_t base = (((size_t)n * 8 + (mt >> 1)) * 64 + l) * 4 + (mt & 1) * 2;
        uint2 u; u.x = pack_bf16(w.x, w.y); u.y = pack_bf16(w.z, w.w);
        *reinterpret_cast<uint2*>(wPack2 + base) = u;
    } else {
        const int t2 = t - nW;                     // < 262,144
        const int n = t2 >> 7, rem = t2 & 127, nt = rem >> 6, l = rem & 63;
        const float4 v = *reinterpret_cast<const float4*>(
            xg + ((size_t)(nt * 32 + (l & 31)) * kNi + n) * 8 + 4 * (l >> 5));
        uint2 u; u.x = pack_bf16(v.x, v.y); u.y = pack_bf16(v.z, v.w);
        *reinterpret_cast<uint2*>(xPack + (size_t)t2 * 2) = u;
    }
}

// C/D layout (m74/m101-verified): col = l&31 (= b),
// row = (reg&3) + 8*(reg>>2) + 4*(l>>5); regs 0-7 -> o = 2*mt, 8-15 -> 2*mt+1.

// ---------------------------------------------------------------------------
// Route. Grid 512 = 256 slabs x 2 b-halves (bid&255 = slab, bid>>8 = nt; the
// pair (bid, bid+256) shares a W slab AND an XCD since 256%8==0).
// 8 waves; wave w owns m-tiles {2w, 2w+1}, covering all 16 mt in-block ->
// softmax's o-reduction closes inside the block (2 KB LDS, 1 barrier/nn,
// double-buffered Z rows).
// SINGLE sweep: x_hat tiles stay in registers from logit step to the
// s-accumulate (no e-stash, no 2nd MFMA pass). Live set ~125 VGPR <= 128 cap.
// PASS==0: pure MFMA accumulate (uniform c; 1/32 applied in finish).
// ---------------------------------------------------------------------------
template<int PASS>
__global__ __launch_bounds__(512, 2)
void caps_route(const unsigned* __restrict__ wPack2, const unsigned* __restrict__ xPack,
                const float* __restrict__ vsumPack, __hip_bfloat16* __restrict__ partial)
{
    __shared__ float Zl[2][8][32];

    const int tid = threadIdx.x;
    const int blk = blockIdx.x & (kSlabs - 1);
    const int nt  = blockIdx.x >> 8;
    const int w   = __builtin_amdgcn_readfirstlane(tid >> 6);  // 0..7
    const int l   = tid & 63;
    const int b32 = l & 31;
    const int b   = nt * 32 + b32;
    const int hi  = l >> 5;

    // vsum fragments for my 2 m-tiles (C-row order, pre-scaled by log2 e)
    float vsp[2][16];
    if (PASS > 0) {
#pragma unroll
        for (int m = 0; m < 2; ++m) {
            const int mt = 2 * w + m;
            const float4* vp = reinterpret_cast<const float4*>(
                vsumPack + (((size_t)mt * 2 + hi) * 64 + b) * 16);
#pragma unroll
            for (int k = 0; k < 4; ++k) {
                const float4 v = vp[k];
                vsp[m][4 * k + 0] = v.x; vsp[m][4 * k + 1] = v.y;
                vsp[m][4 * k + 2] = v.z; vsp[m][4 * k + 3] = v.w;
            }
        }
    }

    float sacc[2][16];
    f16v acc0, acc1;                    // PASS0 accumulators
#pragma unroll
    for (int r = 0; r < 16; ++r) {
        sacc[0][r] = 0.0f; sacc[1][r] = 0.0f;
        acc0[r] = 0.0f;    acc1[r] = 0.0f;
    }

    const int4* wp4 = reinterpret_cast<const int4*>(wPack2);
    const int2* xp2 = reinterpret_cast<const int2*>(xPack);
    const size_t abase = (((size_t)blk * 64 + w) * 64 + l);        // +nn*512
    const size_t xbase = (((size_t)(blk * 8) * 2 + nt) * 64 + l);  // +nn*128

    int4 aw = wp4[abase];
    int2 bx = xp2[xbase];

#pragma unroll
    for (int nn = 0; nn < kNPer; ++nn) {
        int4 awn; int2 bxn;
        if (nn < kNPer - 1) {           // prefetch next frags under the softmax
            awn = wp4[abase + (size_t)(nn + 1) * 512];
            bxn = xp2[xbase + (size_t)(nn + 1) * 128];
        }
        A2 ua0; ua0.i = make_int2(aw.x, aw.y);
        A2 ua1; ua1.i = make_int2(aw.z, aw.w);
        A2 ub;  ub.i  = bx;

        if (PASS == 0) {
            acc0 = mfma_32x32x8_bf16(ua0.s, ub.s, acc0);
            acc1 = mfma_32x32x8_bf16(ua1.s, ub.s, acc1);
        } else {
            f16v t0, t1;
#pragma unroll
            for (int r = 0; r < 16; ++r) { t0[r] = 0.0f; t1[r] = 0.0f; }
            t0 = mfma_32x32x8_bf16(ua0.s, ub.s, t0);
            t1 = mfma_32x32x8_bf16(ua1.s, ub.s, t1);

            // logits (pairwise trees), full d via partner-half shfl
            float e00, e01, e10, e11;
            {
                float a0_ = fmaf(vsp[0][1], t0[1], vsp[0][0] * t0[0]);
                float a1_ = fmaf(vsp[0][3], t0[3], vsp[0][2] * t0[2]);
                float a2_ = fmaf(vsp[0][5], t0[5], vsp[0][4] * t0[4]);
                float a3_ = fmaf(vsp[0][7], t0[7], vsp[0][6] * t0[6]);
                float p0 = (a0_ + a1_) + (a2_ + a3_);
                float b0_ = fmaf(vsp[0][9],  t0[9],  vsp[0][8]  * t0[8]);
                float b1_ = fmaf(vsp[0][11], t0[11], vsp[0][10] * t0[10]);
                float b2_ = fmaf(vsp[0][13], t0[13], vsp[0][12] * t0[12]);
                float b3_ = fmaf(vsp[0][15], t0[15], vsp[0][14] * t0[14]);
                float p1 = (b0_ + b1_) + (b2_ + b3_);
                p0 += __shfl_xor(p0, 32);
                p1 += __shfl_xor(p1, 32);
                e00 = exp2f(p0); e01 = exp2f(p1);
            }
            {
                float a0_ = fmaf(vsp[1][1], t1[1], vsp[1][0] * t1[0]);
                float a1_ = fmaf(vsp[1][3], t1[3], vsp[1][2] * t1[2]);
                float a2_ = fmaf(vsp[1][5], t1[5], vsp[1][4] * t1[4]);
                float a3_ = fmaf(vsp[1][7], t1[7], vsp[1][6] * t1[6]);
                float p0 = (a0_ + a1_) + (a2_ + a3_);
                float b0_ = fmaf(vsp[1][9],  t1[9],  vsp[1][8]  * t1[8]);
                float b1_ = fmaf(vsp[1][11], t1[11], vsp[1][10] * t1[10]);
                float b2_ = fmaf(vsp[1][13], t1[13], vsp[1][12] * t1[12]);
                float b3_ = fmaf(vsp[1][15], t1[15], vsp[1][14] * t1[14]);
                float p1 = (b0_ + b1_) + (b2_ + b3_);
                p0 += __shfl_xor(p0, 32);
                p1 += __shfl_xor(p1, 32);
                e10 = exp2f(p0); e11 = exp2f(p1);
            }

            if (l < 32) Zl[nn & 1][w][l] = (e00 + e01) + (e10 + e11);
            __syncthreads();
            float Z = 0.0f;
#pragma unroll
            for (int w2 = 0; w2 < 8; ++w2) Z += Zl[nn & 1][w2][b32];
            const float rz = __builtin_amdgcn_rcpf(Z);
            const float c00 = e00 * rz, c01 = e01 * rz;
            const float c10 = e10 * rz, c11 = e11 * rz;
#pragma unroll
            for (int r = 0; r < 8; ++r) {
                sacc[0][r]     = fmaf(c00, t0[r],     sacc[0][r]);
                sacc[0][8 + r] = fmaf(c01, t0[8 + r], sacc[0][8 + r]);
                sacc[1][r]     = fmaf(c10, t1[r],     sacc[1][r]);
                sacc[1][8 + r] = fmaf(c11, t1[8 + r], sacc[1][8 + r]);
            }
        }
        aw = awn; bx = bxn;
    }

    // partial[slab][b][od] bf16; 4 consecutive od per quad -> uint2
#pragma unroll
    for (int m = 0; m < 2; ++m) {
        const int mt = 2 * w + m;
#pragma unroll
        for (int q = 0; q < 4; ++q) {
            const int od = mt * 32 + 8 * q + 4 * hi;
            float v0, v1, v2, v3;
            if (PASS == 0) {
                const f16v& a = (m == 0) ? acc0 : acc1;
                v0 = a[4 * q + 0]; v1 = a[4 * q + 1];
                v2 = a[4 * q + 2]; v3 = a[4 * q + 3];
            } else {
                v0 = sacc[m][4 * q + 0]; v1 = sacc[m][4 * q + 1];
                v2 = sacc[m][4 * q + 2]; v3 = sacc[m][4 * q + 3];
            }
            uint2 u; u.x = pack_bf16(v0, v1); u.y = pack_bf16(v2, v3);
            *reinterpret_cast<uint2*>(
                partial + ((size_t)blk * kB + b) * kSeg + od) = u;
        }
    }
}

// ---------------------------------------------------------------------------
// Finish: sum partials [slab][b][od] over 256 slabs -> s; squash; update
// vsum (+ vsumPack, log2e-scaled, C-row order) / out.
// 512 threads = 4 slab-groups x 128 od lanes.
// ---------------------------------------------------------------------------
template<int PASS>
__global__ __launch_bounds__(512, 2)
void caps_finish(const __hip_bfloat16* __restrict__ partial,
                 float* __restrict__ vsum, float* __restrict__ vsumPack,
                 float* __restrict__ out)
{
    const int b  = blockIdx.x >> 2;
    const int q  = blockIdx.x & 3;
    const int t  = threadIdx.x;
    const int tl = t & 127;
    const int cg = t >> 7;            // slab group 0..3 (64 slabs each)
    const int od = q * 128 + tl;

    const __hip_bfloat16* p = partial
        + ((size_t)(cg * 64) * kB + b) * kSeg + od;
    float s = 0.0f;
#pragma unroll 16
    for (int k = 0; k < 64; ++k)
        s += __bfloat162float(p[(size_t)k * (kB * kSeg)]);

    __shared__ float red[4][128];
    __shared__ float sq[128];
    __shared__ float fo[8];
    red[cg][tl] = s;
    __syncthreads();
    if (t < 128) {
        s = (red[0][tl] + red[1][tl]) + (red[2][tl] + red[3][tl]);
        if (PASS == 0) s *= (1.0f / 32.0f);   // uniform coupling 1/No
        sq[tl] = s * s;
    }
    __syncthreads();
    if (t < 8) {
        float n2 = 0.0f;
#pragma unroll
        for (int d = 0; d < 16; ++d) n2 += sq[t * 16 + d];
        fo[t] = sqrtf(n2) / (1.0f + n2);   // ||s|| / (1 + ||s||^2)
    }
    __syncthreads();
    if (t < 128) {
        const float v = fo[tl >> 4] * s;
        float nv = v;
        if (PASS == 0) {
            vsum[(size_t)b * kSeg + od] = v;
        } else if (PASS == 1) {
            nv = vsum[(size_t)b * kSeg + od] + v;
            vsum[(size_t)b * kSeg + od] = nv;
        } else {
            out[(size_t)b * kSeg + od] = v;
        }
        if (PASS < 2) {
            // invert C-row map: row = (reg&3) + 8*(reg>>2) + 4*hi
            const int mt = od >> 5, r5 = od & 31;
            const int hi = (r5 >> 2) & 1, reg = (r5 & 3) | ((r5 >> 3) << 2);
            vsumPack[(((size_t)mt * 2 + hi) * 64 + b) * 16 + reg] =
                nv * 1.44269504f;
        }
    }
}

// ---------------------------------------------------------------------------
extern "C" void kernel_launch(void* const* d_in, const int* in_sizes, int n_in,
                              void* d_out, int out_size, void* d_ws, size_t ws_size,
                              hipStream_t stream)
{
    const float* x = (const float*)d_in[0];   // (64, 2048, 8)
    const float* W = (const float*)d_in[1];   // (2048, 32, 16, 8)
    float* out = (float*)d_out;               // (64, 32, 16)

    // ws layout
    char* base = (char*)d_ws;
    __hip_bfloat16* partial = (__hip_bfloat16*)base;                  // 16.78 MB
    base += (size_t)kSlabs * kB * kSeg * sizeof(__hip_bfloat16);
    float* vsum = (float*)base;                                       // 128 KB
    base += (size_t)kB * kSeg * sizeof(float);
    float* vsumPack = (float*)base;                                   // 128 KB
    base += (size_t)16 * 2 * 64 * 16 * sizeof(float);
    unsigned* wPack2 = (unsigned*)base;                               // 16.78 MB
    base += (size_t)kNi * 16 * 64 * 2 * sizeof(unsigned);
    unsigned* xPack = (unsigned*)base;                                // 2 MB

    caps_prep<<<dim3(9216), dim3(256), 0, stream>>>(x, W, wPack2, xPack);

    const dim3 gr(kSlabs * 2), br(512);
    const dim3 gf(kB * 4), bf(512);

    caps_route<0><<<gr, br, 0, stream>>>(wPack2, xPack, vsumPack, partial);
    caps_finish<0><<<gf, bf, 0, stream>>>(partial, vsum, vsumPack, out);
    caps_route<1><<<gr, br, 0, stream>>>(wPack2, xPack, vsumPack, partial);
    caps_finish<1><<<gf, bf, 0, stream>>>(partial, vsum, vsumPack, out);
    caps_route<1><<<gr, br, 0, stream>>>(wPack2, xPack, vsumPack, partial);
    caps_finish<2><<<gf, bf, 0, stream>>>(partial, vsum, vsumPack, out);
}

// Round 11
// 85.099 us; speedup vs baseline: 2.0287x; 2.0287x over previous
//
#include <hip/hip_runtime.h>
#include <hip/hip_bf16.h>
#include <math.h>

namespace {
constexpr int kB  = 64;
constexpr int kNi = 2048;
constexpr int kNo = 32;
constexpr int kDo = 16;
constexpr int kSeg   = kNo * kDo;      // 512 od
constexpr int kSlabs = 256;            // n-slabs
constexpr int kNPer  = kNi / kSlabs;   // 8 n per slab
}

typedef __attribute__((ext_vector_type(4)))  short s4;    // 4 bf16 (2 VGPR)
typedef __attribute__((ext_vector_type(16))) float f16v;  // MFMA C/D

__device__ __forceinline__ f16v mfma_32x32x8_bf16(s4 a, s4 b, f16v c) {
#if __has_builtin(__builtin_amdgcn_mfma_f32_32x32x8bf16_1k)
    return __builtin_amdgcn_mfma_f32_32x32x8bf16_1k(a, b, c, 0, 0, 0);
#else
    asm("v_mfma_f32_32x32x8_bf16 %0, %1, %2, %0" : "+v"(c) : "v"(a), "v"(b));
    return c;
#endif
}

__device__ __forceinline__ unsigned pack_bf16(float lo, float hi) {
    union { __hip_bfloat162 h; unsigned u; } v;
    v.h = __float22bfloat162_rn(make_float2(lo, hi));
    return v.u;
}
__device__ __forceinline__ float bf_lo(unsigned u) { return __uint_as_float(u << 16); }
__device__ __forceinline__ float bf_hi(unsigned u) { return __uint_as_float(u & 0xffff0000u); }

union A2 { int2 i; s4 s; };

// ---------------------------------------------------------------------------
// Prep (verified r10): pack W and x into 32x32x8 MFMA fragment order, bf16.
// wPack2 int4 idx ((n*8+w)*64+l): slots {0,1}=mt 2w, {2,3}=mt 2w+1,
//   value = W[n][mt*32+(l&31)][4*(l>>5)+j].
// xPack int2 idx ((n*2+nt)*64+l) = x[nt*32+(l&31)][n][4*(l>>5)+j].
// ---------------------------------------------------------------------------
__global__ __launch_bounds__(256, 4)
void caps_prep(const float* __restrict__ xg, const float* __restrict__ Wg,
               unsigned* __restrict__ wPack2, unsigned* __restrict__ xPack)
{
    const int t = blockIdx.x * 256 + threadIdx.x;
    const int nW = kNi * 16 * 64;
    if (t < nW) {
        const int n = t >> 10, rem = t & 1023, mt = rem >> 6, l = rem & 63;
        const float4 w = *reinterpret_cast<const float4*>(
            Wg + ((size_t)n * kSeg + mt * 32 + (l & 31)) * 8 + 4 * (l >> 5));
        const size_t base = (((size_t)n * 8 + (mt >> 1)) * 64 + l) * 4 + (mt & 1) * 2;
        uint2 u; u.x = pack_bf16(w.x, w.y); u.y = pack_bf16(w.z, w.w);
        *reinterpret_cast<uint2*>(wPack2 + base) = u;
    } else {
        const int t2 = t - nW;
        const int n = t2 >> 7, rem = t2 & 127, nt = rem >> 6, l = rem & 63;
        const float4 v = *reinterpret_cast<const float4*>(
            xg + ((size_t)(nt * 32 + (l & 31)) * kNi + n) * 8 + 4 * (l >> 5));
        uint2 u; u.x = pack_bf16(v.x, v.y); u.y = pack_bf16(v.z, v.w);
        *reinterpret_cast<uint2*>(xPack + (size_t)t2 * 2) = u;
    }
}

// C/D layout (m74/m101-verified): col = l&31 (= b),
// row = (reg&3)+8*(reg>>2)+4*(l>>5); regs 0-7 -> o=2mt, regs 8-15 -> o=2mt+1.

// ---------------------------------------------------------------------------
// Logits kernel: c[n,o,b] = softmax_o(vsum . x_hat), written as packed bf16
// (one uint per (n,mt,b): lo = o even, hi = o odd). Grid 512 = slab x nt.
// Wave w owns mt {2w, 2w+1}; block covers all 16 mt -> Z closes in-block.
// Two 4-nn batches, double-buffered Zl -> 2 barriers total.
// Live set ~95 VGPR (vsp 32 + e 16 + transient tiles) -> fits 128 cap.
// ---------------------------------------------------------------------------
__global__ __launch_bounds__(512, 2)
void caps_logits(const unsigned* __restrict__ wPack2, const unsigned* __restrict__ xPack,
                 const float* __restrict__ vsumPack, unsigned* __restrict__ cbuf)
{
    __shared__ float Zl[2][8][4][32];

    const int tid = threadIdx.x;
    const int blk = blockIdx.x & (kSlabs - 1);
    const int nt  = blockIdx.x >> 8;
    const int w   = __builtin_amdgcn_readfirstlane(tid >> 6);
    const int l   = tid & 63;
    const int b32 = l & 31;
    const int b   = nt * 32 + b32;
    const int hi  = l >> 5;

    // vsum fragments (C-row order, pre-scaled by log2 e)
    float vsp[2][16];
#pragma unroll
    for (int m = 0; m < 2; ++m) {
        const int mt = 2 * w + m;
        const float4* vp = reinterpret_cast<const float4*>(
            vsumPack + (((size_t)mt * 2 + hi) * 64 + b) * 16);
#pragma unroll
        for (int k = 0; k < 4; ++k) {
            const float4 v = vp[k];
            vsp[m][4 * k + 0] = v.x; vsp[m][4 * k + 1] = v.y;
            vsp[m][4 * k + 2] = v.z; vsp[m][4 * k + 3] = v.w;
        }
    }

    const int4* wp4 = reinterpret_cast<const int4*>(wPack2);
    const int2* xp2 = reinterpret_cast<const int2*>(xPack);
    const size_t abase = ((size_t)blk * 64 + w) * 64 + l;          // +nn*512
    const size_t xbase = ((size_t)blk * 16 + nt) * 64 + l;         // +nn*128

    for (int h = 0; h < 2; ++h) {
        float e[4][4];
#pragma unroll
        for (int k = 0; k < 4; ++k) {
            const int nn = h * 4 + k;
            const int4 aw = wp4[abase + (size_t)nn * 512];
            const int2 bx = xp2[xbase + (size_t)nn * 128];
            A2 ua0; ua0.i = make_int2(aw.x, aw.y);
            A2 ua1; ua1.i = make_int2(aw.z, aw.w);
            A2 ub;  ub.i  = bx;
            f16v t0, t1;
#pragma unroll
            for (int r = 0; r < 16; ++r) { t0[r] = 0.0f; t1[r] = 0.0f; }
            t0 = mfma_32x32x8_bf16(ua0.s, ub.s, t0);
            t1 = mfma_32x32x8_bf16(ua1.s, ub.s, t1);
            {
                float a0_ = fmaf(vsp[0][1], t0[1], vsp[0][0] * t0[0]);
                float a1_ = fmaf(vsp[0][3], t0[3], vsp[0][2] * t0[2]);
                float a2_ = fmaf(vsp[0][5], t0[5], vsp[0][4] * t0[4]);
                float a3_ = fmaf(vsp[0][7], t0[7], vsp[0][6] * t0[6]);
                float p0 = (a0_ + a1_) + (a2_ + a3_);
                float b0_ = fmaf(vsp[0][9],  t0[9],  vsp[0][8]  * t0[8]);
                float b1_ = fmaf(vsp[0][11], t0[11], vsp[0][10] * t0[10]);
                float b2_ = fmaf(vsp[0][13], t0[13], vsp[0][12] * t0[12]);
                float b3_ = fmaf(vsp[0][15], t0[15], vsp[0][14] * t0[14]);
                float p1 = (b0_ + b1_) + (b2_ + b3_);
                p0 += __shfl_xor(p0, 32);
                p1 += __shfl_xor(p1, 32);
                e[k][0] = exp2f(p0); e[k][1] = exp2f(p1);
            }
            {
                float a0_ = fmaf(vsp[1][1], t1[1], vsp[1][0] * t1[0]);
                float a1_ = fmaf(vsp[1][3], t1[3], vsp[1][2] * t1[2]);
                float a2_ = fmaf(vsp[1][5], t1[5], vsp[1][4] * t1[4]);
                float a3_ = fmaf(vsp[1][7], t1[7], vsp[1][6] * t1[6]);
                float p0 = (a0_ + a1_) + (a2_ + a3_);
                float b0_ = fmaf(vsp[1][9],  t1[9],  vsp[1][8]  * t1[8]);
                float b1_ = fmaf(vsp[1][11], t1[11], vsp[1][10] * t1[10]);
                float b2_ = fmaf(vsp[1][13], t1[13], vsp[1][12] * t1[12]);
                float b3_ = fmaf(vsp[1][15], t1[15], vsp[1][14] * t1[14]);
                float p1 = (b0_ + b1_) + (b2_ + b3_);
                p0 += __shfl_xor(p0, 32);
                p1 += __shfl_xor(p1, 32);
                e[k][2] = exp2f(p0); e[k][3] = exp2f(p1);
            }
            if (l < 32)
                Zl[h][w][k][l] = (e[k][0] + e[k][1]) + (e[k][2] + e[k][3]);
        }
        __syncthreads();
#pragma unroll
        for (int k = 0; k < 4; ++k) {
            float Z = 0.0f;
#pragma unroll
            for (int w2 = 0; w2 < 8; ++w2) Z += Zl[h][w2][k][b32];
            const float rz = __builtin_amdgcn_rcpf(Z);
            if (l < 32) {
                const size_t idx =
                    (((size_t)(blk * 8 + h * 4 + k) * 16) + 2 * w) * 64 + b;
                cbuf[idx]      = pack_bf16(e[k][0] * rz, e[k][1] * rz);
                cbuf[idx + 64] = pack_bf16(e[k][2] * rz, e[k][3] * rz);
            }
        }
    }
}

// ---------------------------------------------------------------------------
// Accumulate kernel: sacc[od,b] = sum_n c * x_hat (PASS1) or sum_n x_hat
// (PASS0, uniform c; 1/32 applied in finish). Grid 512 = slab x nt.
// Live set ~90 VGPR (sacc 32 + transient tiles; no vsp) -> fits 128 cap.
// ---------------------------------------------------------------------------
template<int PASS>
__global__ __launch_bounds__(512, 2)
void caps_accum(const unsigned* __restrict__ wPack2, const unsigned* __restrict__ xPack,
                const unsigned* __restrict__ cbuf, __hip_bfloat16* __restrict__ partial)
{
    const int tid = threadIdx.x;
    const int blk = blockIdx.x & (kSlabs - 1);
    const int nt  = blockIdx.x >> 8;
    const int w   = __builtin_amdgcn_readfirstlane(tid >> 6);
    const int l   = tid & 63;
    const int b32 = l & 31;
    const int b   = nt * 32 + b32;
    const int hi  = l >> 5;

    float sacc[2][16];
    f16v acc0, acc1;
#pragma unroll
    for (int r = 0; r < 16; ++r) {
        sacc[0][r] = 0.0f; sacc[1][r] = 0.0f;
        acc0[r] = 0.0f;    acc1[r] = 0.0f;
    }

    const int4* wp4 = reinterpret_cast<const int4*>(wPack2);
    const int2* xp2 = reinterpret_cast<const int2*>(xPack);
    const size_t abase = ((size_t)blk * 64 + w) * 64 + l;
    const size_t xbase = ((size_t)blk * 16 + nt) * 64 + l;
    const size_t cbase = ((size_t)blk * 128 + 2 * w) * 64 + b;     // +nn*1024

#pragma unroll 2
    for (int nn = 0; nn < kNPer; ++nn) {
        const int4 aw = wp4[abase + (size_t)nn * 512];
        const int2 bx = xp2[xbase + (size_t)nn * 128];
        A2 ua0; ua0.i = make_int2(aw.x, aw.y);
        A2 ua1; ua1.i = make_int2(aw.z, aw.w);
        A2 ub;  ub.i  = bx;

        if (PASS == 0) {
            acc0 = mfma_32x32x8_bf16(ua0.s, ub.s, acc0);
            acc1 = mfma_32x32x8_bf16(ua1.s, ub.s, acc1);
        } else {
            const unsigned cp0 = cbuf[cbase + (size_t)nn * 1024];
            const unsigned cp1 = cbuf[cbase + (size_t)nn * 1024 + 64];
            f16v t0, t1;
#pragma unroll
            for (int r = 0; r < 16; ++r) { t0[r] = 0.0f; t1[r] = 0.0f; }
            t0 = mfma_32x32x8_bf16(ua0.s, ub.s, t0);
            t1 = mfma_32x32x8_bf16(ua1.s, ub.s, t1);
            const float c00 = bf_lo(cp0), c01 = bf_hi(cp0);
            const float c10 = bf_lo(cp1), c11 = bf_hi(cp1);
#pragma unroll
            for (int r = 0; r < 8; ++r) {
                sacc[0][r]     = fmaf(c00, t0[r],     sacc[0][r]);
                sacc[0][8 + r] = fmaf(c01, t0[8 + r], sacc[0][8 + r]);
                sacc[1][r]     = fmaf(c10, t1[r],     sacc[1][r]);
                sacc[1][8 + r] = fmaf(c11, t1[8 + r], sacc[1][8 + r]);
            }
        }
    }

    // partial[slab][b][od] bf16
#pragma unroll
    for (int m = 0; m < 2; ++m) {
        const int mt = 2 * w + m;
#pragma unroll
        for (int q = 0; q < 4; ++q) {
            const int od = mt * 32 + 8 * q + 4 * hi;
            float v0, v1, v2, v3;
            if (PASS == 0) {
                const f16v& a = (m == 0) ? acc0 : acc1;
                v0 = a[4 * q + 0]; v1 = a[4 * q + 1];
                v2 = a[4 * q + 2]; v3 = a[4 * q + 3];
            } else {
                v0 = sacc[m][4 * q + 0]; v1 = sacc[m][4 * q + 1];
                v2 = sacc[m][4 * q + 2]; v3 = sacc[m][4 * q + 3];
            }
            uint2 u; u.x = pack_bf16(v0, v1); u.y = pack_bf16(v2, v3);
            *reinterpret_cast<uint2*>(
                partial + ((size_t)blk * kB + b) * kSeg + od) = u;
        }
    }
}

// ---------------------------------------------------------------------------
// Finish: sum partials [slab][b][od] over 256 slabs -> s; squash; update
// vsum (+ vsumPack, log2e-scaled, C-row order) / out.
// ---------------------------------------------------------------------------
template<int PASS>
__global__ __launch_bounds__(512, 2)
void caps_finish(const __hip_bfloat16* __restrict__ partial,
                 float* __restrict__ vsum, float* __restrict__ vsumPack,
                 float* __restrict__ out)
{
    const int b  = blockIdx.x >> 2;
    const int q  = blockIdx.x & 3;
    const int t  = threadIdx.x;
    const int tl = t & 127;
    const int cg = t >> 7;
    const int od = q * 128 + tl;

    const __hip_bfloat16* p = partial
        + ((size_t)(cg * 64) * kB + b) * kSeg + od;
    float s = 0.0f;
#pragma unroll 16
    for (int k = 0; k < 64; ++k)
        s += __bfloat162float(p[(size_t)k * (kB * kSeg)]);

    __shared__ float red[4][128];
    __shared__ float sq[128];
    __shared__ float fo[8];
    red[cg][tl] = s;
    __syncthreads();
    if (t < 128) {
        s = (red[0][tl] + red[1][tl]) + (red[2][tl] + red[3][tl]);
        if (PASS == 0) s *= (1.0f / 32.0f);
        sq[tl] = s * s;
    }
    __syncthreads();
    if (t < 8) {
        float n2 = 0.0f;
#pragma unroll
        for (int d = 0; d < 16; ++d) n2 += sq[t * 16 + d];
        fo[t] = sqrtf(n2) / (1.0f + n2);
    }
    __syncthreads();
    if (t < 128) {
        const float v = fo[tl >> 4] * s;
        float nv = v;
        if (PASS == 0) {
            vsum[(size_t)b * kSeg + od] = v;
        } else if (PASS == 1) {
            nv = vsum[(size_t)b * kSeg + od] + v;
            vsum[(size_t)b * kSeg + od] = nv;
        } else {
            out[(size_t)b * kSeg + od] = v;
        }
        if (PASS < 2) {
            const int mt = od >> 5, r5 = od & 31;
            const int hi = (r5 >> 2) & 1, reg = (r5 & 3) | ((r5 >> 3) << 2);
            vsumPack[(((size_t)mt * 2 + hi) * 64 + b) * 16 + reg] =
                nv * 1.44269504f;
        }
    }
}

// ---------------------------------------------------------------------------
extern "C" void kernel_launch(void* const* d_in, const int* in_sizes, int n_in,
                              void* d_out, int out_size, void* d_ws, size_t ws_size,
                              hipStream_t stream)
{
    const float* x = (const float*)d_in[0];   // (64, 2048, 8)
    const float* W = (const float*)d_in[1];   // (2048, 32, 16, 8)
    float* out = (float*)d_out;               // (64, 32, 16)

    char* base = (char*)d_ws;
    __hip_bfloat16* partial = (__hip_bfloat16*)base;                  // 16.78 MB
    base += (size_t)kSlabs * kB * kSeg * sizeof(__hip_bfloat16);
    float* vsum = (float*)base;                                       // 128 KB
    base += (size_t)kB * kSeg * sizeof(float);
    float* vsumPack = (float*)base;                                   // 128 KB
    base += (size_t)16 * 2 * 64 * 16 * sizeof(float);
    unsigned* wPack2 = (unsigned*)base;                               // 16.78 MB
    base += (size_t)kNi * 16 * 64 * 2 * sizeof(unsigned);
    unsigned* xPack = (unsigned*)base;                                // 2 MB
    base += (size_t)kNi * 2 * 64 * 4 * sizeof(unsigned);
    unsigned* cbuf = (unsigned*)base;                                 // 8.39 MB

    caps_prep<<<dim3(9216), dim3(256), 0, stream>>>(x, W, wPack2, xPack);

    const dim3 gr(kSlabs * 2), br(512);
    const dim3 gf(kB * 4), bf(512);

    caps_accum<0><<<gr, br, 0, stream>>>(wPack2, xPack, cbuf, partial);
    caps_finish<0><<<gf, bf, 0, stream>>>(partial, vsum, vsumPack, out);
    caps_logits<<<gr, br, 0, stream>>>(wPack2, xPack, vsumPack, cbuf);
    caps_accum<1><<<gr, br, 0, stream>>>(wPack2, xPack, cbuf, partial);
    caps_finish<1><<<gf, bf, 0, stream>>>(partial, vsum, vsumPack, out);
    caps_logits<<<gr, br, 0, stream>>>(wPack2, xPack, vsumPack, cbuf);
    caps_accum<1><<<gr, br, 0, stream>>>(wPack2, xPack, cbuf, partial);
    caps_finish<2><<<gf, bf, 0, stream>>>(partial, vsum, vsumPack, out);
}